// Round 1
// baseline (665.229 us; speedup 1.0000x reference)
//
#include <hip/hip_runtime.h>

// Problem constants from the reference: B=64, N=64, P=512, M=512.
#define B_ 64
#define N_ 64
#define P_ 512
#define M_ 512

// One block per (b, p) pair. 128 threads; each thread owns one float4 slot
// in each of the three M-sized output chunks (M/4 = 128 float4).
__global__ __launch_bounds__(128) void ooi_gather_kernel(
    const float* __restrict__ obj_ft,        // [B, N, M]
    const float* __restrict__ node_emb,      // [B, N, M]
    const float* __restrict__ edge_emb,      // [B, N, N, M]
    const int*   __restrict__ pairs,         // [B, P, 2] (int32)
    float* __restrict__ out)                 // [B, P, 3M]
{
    const int bp = blockIdx.x;               // [0, B*P)
    const int b  = bp >> 9;                  // bp / P  (P = 512)
    const int t  = threadIdx.x;              // [0, 128) float4 index

    // Wave-uniform broadcast loads of the pair indices.
    const int i0 = pairs[2 * bp + 0];
    const int i1 = pairs[2 * bp + 1];

    const size_t bn0 = (size_t)(b * N_ + i0);
    const size_t bn1 = (size_t)(b * N_ + i1);

    const float4* n0  = (const float4*)(node_emb + bn0 * M_);
    const float4* n1  = (const float4*)(node_emb + bn1 * M_);
    const float4* o0  = (const float4*)(obj_ft   + bn0 * M_);
    const float4* o1  = (const float4*)(obj_ft   + bn1 * M_);
    const float4* e01 = (const float4*)(edge_emb + (bn0 * N_ + i1) * (size_t)M_);
    const float4* e10 = (const float4*)(edge_emb + (bn1 * N_ + i0) * (size_t)M_);

    float4* outp = (float4*)(out + (size_t)bp * (3 * M_));

    // chunk 0: 0.5 * (node[i0] + obj[i0])
    {
        float4 a = n0[t], c = o0[t], r;
        r.x = 0.5f * (a.x + c.x);
        r.y = 0.5f * (a.y + c.y);
        r.z = 0.5f * (a.z + c.z);
        r.w = 0.5f * (a.w + c.w);
        outp[t] = r;
    }
    // chunk 1: 0.5 * (node[i1] + obj[i1])
    {
        float4 a = n1[t], c = o1[t], r;
        r.x = 0.5f * (a.x + c.x);
        r.y = 0.5f * (a.y + c.y);
        r.z = 0.5f * (a.z + c.z);
        r.w = 0.5f * (a.w + c.w);
        outp[128 + t] = r;
    }
    // chunk 2: 0.5 * (edge[i0,i1] + edge[i1,i0])
    {
        float4 a = e01[t], c = e10[t], r;
        r.x = 0.5f * (a.x + c.x);
        r.y = 0.5f * (a.y + c.y);
        r.z = 0.5f * (a.z + c.z);
        r.w = 0.5f * (a.w + c.w);
        outp[256 + t] = r;
    }
}

extern "C" void kernel_launch(void* const* d_in, const int* in_sizes, int n_in,
                              void* d_out, int out_size, void* d_ws, size_t ws_size,
                              hipStream_t stream) {
    const float* obj_ft   = (const float*)d_in[0];
    const float* node_emb = (const float*)d_in[1];
    const float* edge_emb = (const float*)d_in[2];
    const int*   pairs    = (const int*)d_in[3];
    float* out = (float*)d_out;

    dim3 grid(B_ * P_);   // 32768 blocks
    dim3 block(128);
    ooi_gather_kernel<<<grid, block, 0, stream>>>(obj_ft, node_emb, edge_emb,
                                                  pairs, out);
}